// Round 1
// baseline (329.737 us; speedup 1.0000x reference)
//
#include <hip/hip_runtime.h>
#include <hip/hip_bf16.h>

// ---------- types ----------
typedef __bf16 bf16x8 __attribute__((ext_vector_type(8)));
typedef float  f32x4  __attribute__((ext_vector_type(4)));

#define GLOAD_LDS16(gptr, lptr)                                                  \
  __builtin_amdgcn_global_load_lds(                                              \
      (const __attribute__((address_space(1))) void*)(gptr),                     \
      (__attribute__((address_space(3))) void*)(lptr), 16, 0, 0)

__device__ __forceinline__ unsigned short f2bf(float f) {
  __hip_bfloat16 h = __float2bfloat16(f);
  return __builtin_bit_cast(unsigned short, h);
}

// max over the 32-lane group this lane belongs to (masks <32 never cross the
// 32-lane halves of a wave64)
__device__ __forceinline__ float groupmax32(float v) {
  v = fmaxf(v, __shfl_xor(v, 1));
  v = fmaxf(v, __shfl_xor(v, 2));
  v = fmaxf(v, __shfl_xor(v, 4));
  v = fmaxf(v, __shfl_xor(v, 8));
  v = fmaxf(v, __shfl_xor(v, 16));
  return v;
}

// Fake-quant 4 values (one lane's slice of a 128-elem block spread over 32
// lanes x 4 elems). Matches ref: amax->clip 1e-12, scale=448/amax,
// clip(x*scale,+-448), RNE fp8 e4m3 (HW cvt, OCP on gfx950), deq = q/scale.
__device__ __forceinline__ void fq_e4m3_4(const float* __restrict__ in,
                                          float* __restrict__ out) {
  float am = fmaxf(fmaxf(fabsf(in[0]), fabsf(in[1])),
                   fmaxf(fabsf(in[2]), fabsf(in[3])));
  am = groupmax32(am);
  am = fmaxf(am, 1e-12f);
  const float scale = 448.0f / am;
  float c0 = fminf(fmaxf(in[0] * scale, -448.0f), 448.0f);
  float c1 = fminf(fmaxf(in[1] * scale, -448.0f), 448.0f);
  float c2 = fminf(fmaxf(in[2] * scale, -448.0f), 448.0f);
  float c3 = fminf(fmaxf(in[3] * scale, -448.0f), 448.0f);
  int pk = __builtin_amdgcn_cvt_pk_fp8_f32(c0, c1, 0, false);
  pk = __builtin_amdgcn_cvt_pk_fp8_f32(c2, c3, pk, true);
  out[0] = __builtin_amdgcn_cvt_f32_fp8(pk, 0) / scale;
  out[1] = __builtin_amdgcn_cvt_f32_fp8(pk, 1) / scale;
  out[2] = __builtin_amdgcn_cvt_f32_fp8(pk, 2) / scale;
  out[3] = __builtin_amdgcn_cvt_f32_fp8(pk, 3) / scale;
}

// ---------- activation quant: one block per row of x2d (K=1024) ----------
__global__ __launch_bounds__(256) void quant_x_k(const float* __restrict__ x,
                                                 unsigned short* __restrict__ xq) {
  const size_t row = blockIdx.x;
  const int tid = threadIdx.x;
  const float4 v = ((const float4*)(x + row * 1024))[tid];
  float in[4] = {v.x, v.y, v.z, v.w};
  float dq[4];
  fq_e4m3_4(in, dq);
  union { ushort4 u; unsigned short s[4]; } pk;
  pk.s[0] = f2bf(dq[0]); pk.s[1] = f2bf(dq[1]);
  pk.s[2] = f2bf(dq[2]); pk.s[3] = f2bf(dq[3]);
  ((ushort4*)(xq + row * 1024))[tid] = pk.u;
}

// ---------- weight dual-quant: one block per row of W (K=1024) ----------
__global__ __launch_bounds__(256) void quant_w_k(const float* __restrict__ w,
                                                 unsigned short* __restrict__ wq) {
  const size_t row = blockIdx.x;
  const int tid = threadIdx.x;
  const float4 v = ((const float4*)(w + row * 1024))[tid];
  float in[4] = {v.x, v.y, v.z, v.w};
  float hi[4], res[4], lo[4];
  fq_e4m3_4(in, hi);
#pragma unroll
  for (int i = 0; i < 4; ++i) res[i] = in[i] - hi[i];
  fq_e4m3_4(res, lo);
  union { ushort4 u; unsigned short s[4]; } pk;
#pragma unroll
  for (int i = 0; i < 4; ++i) pk.s[i] = f2bf(hi[i] + lo[i]);
  ((ushort4*)(wq + row * 1024))[tid] = pk.u;
}

// ---------- GEMM: C[M,N] = A[M,K] * B[N,K]^T + bias, bf16 in fp32 out ----
#define BM 128
#define BN 128
#define BK 64

__global__ __launch_bounds__(256) void gemm_bt_bias(
    const unsigned short* __restrict__ A,   // bf16 bits [M,K]
    const unsigned short* __restrict__ B,   // bf16 bits [N,K]
    const float* __restrict__ bias,         // [N]
    float* __restrict__ C,                  // [M,N]
    int M, int N, int K) {
  __shared__ unsigned short ldsA[BM * BK];  // 16 KB, row-major 128x64, no pad
  __shared__ unsigned short ldsB[BN * BK];  // 16 KB

  const int tid  = threadIdx.x;
  const int wave = tid >> 6;
  const int lane = tid & 63;
  const int ntn  = N / BN;
  const int bn   = blockIdx.x % ntn;
  const int bm   = blockIdx.x / ntn;
  const int wr   = wave >> 1;   // 0..1 (M dir)
  const int wc   = wave & 1;    // 0..1 (N dir)

  f32x4 acc[4][4] = {};

  // staging: wave covers tile rows [wave*32, wave*32+32), 4 chunks of 8 rows.
  // lane i -> row (lane>>3), 16B group (lane&7). LDS dest = base + lane*16B.
  const int rload = wave * 32 + (lane >> 3);
  const int cload = (lane & 7) * 8;
  const unsigned short* gA = A + (size_t)(bm * BM + rload) * K + cload;
  const unsigned short* gB = B + (size_t)(bn * BN + rload) * K + cload;
  unsigned short* lA = ldsA + wave * 2048 + lane * 8;
  unsigned short* lB = ldsB + wave * 2048 + lane * 8;

  for (int kt = 0; kt < K; kt += BK) {
    __syncthreads();
#pragma unroll
    for (int t = 0; t < 4; ++t) {
      GLOAD_LDS16(gA + (size_t)(t * 8) * K + kt, lA + t * 512);
      GLOAD_LDS16(gB + (size_t)(t * 8) * K + kt, lB + t * 512);
    }
    __syncthreads();

#pragma unroll
    for (int kc = 0; kc < 2; ++kc) {
      const int kOff = kc * 32 + (lane >> 4) * 8;
      const int fRow = lane & 15;
      bf16x8 af[4], bfr[4];
#pragma unroll
      for (int i = 0; i < 4; ++i)
        af[i] = *(const bf16x8*)&ldsA[(wr * 64 + i * 16 + fRow) * BK + kOff];
#pragma unroll
      for (int j = 0; j < 4; ++j)
        bfr[j] = *(const bf16x8*)&ldsB[(wc * 64 + j * 16 + fRow) * BK + kOff];
#pragma unroll
      for (int i = 0; i < 4; ++i)
#pragma unroll
        for (int j = 0; j < 4; ++j)
          acc[i][j] = __builtin_amdgcn_mfma_f32_16x16x32_bf16(af[i], bfr[j],
                                                              acc[i][j], 0, 0, 0);
    }
  }

  // epilogue: C/D map col=lane&15, row=(lane>>4)*4+reg  [m89/m91 verified]
  const int    n0 = bn * BN + wc * 64 + (lane & 15);
  const size_t m0 = (size_t)bm * BM + wr * 64 + ((lane >> 4) << 2);
#pragma unroll
  for (int j = 0; j < 4; ++j) {
    const int col = n0 + j * 16;
    const float bv = bias[col];
#pragma unroll
    for (int i = 0; i < 4; ++i) {
      const size_t base = (m0 + (size_t)i * 16) * N + col;
#pragma unroll
      for (int r = 0; r < 4; ++r)
        C[base + (size_t)r * N] = acc[i][j][r] + bv;
    }
  }
}

// ---------- launch ----------
extern "C" void kernel_launch(void* const* d_in, const int* in_sizes, int n_in,
                              void* d_out, int out_size, void* d_ws, size_t ws_size,
                              hipStream_t stream) {
  const float* x    = (const float*)d_in[0];
  const float* w    = (const float*)d_in[1];
  const float* bias = (const float*)d_in[2];

  const int DOUT = in_sizes[2];            // 1024
  const int DIN  = in_sizes[1] / DOUT;     // 1024
  const int M    = in_sizes[0] / DIN;      // 32768

  unsigned short* xq = (unsigned short*)d_ws;                  // M*K bf16 = 64 MB
  unsigned short* wq = xq + (size_t)M * DIN;                   // N*K bf16 =  2 MB

  hipLaunchKernelGGL(quant_x_k, dim3(M), dim3(256), 0, stream, x, xq);
  hipLaunchKernelGGL(quant_w_k, dim3(DOUT), dim3(256), 0, stream, w, wq);

  const int grid = (M / BM) * (DOUT / BN);
  hipLaunchKernelGGL(gemm_bt_bias, dim3(grid), dim3(256), 0, stream,
                     xq, wq, bias, (float*)d_out, M, DOUT, DIN);
}

// Round 2
// 328.603 us; speedup vs baseline: 1.0034x; 1.0034x over previous
//
#include <hip/hip_runtime.h>
#include <hip/hip_bf16.h>

// ---------- types ----------
typedef __bf16 bf16x8 __attribute__((ext_vector_type(8)));
typedef float  f32x4  __attribute__((ext_vector_type(4)));

#define GLOAD_LDS16(gptr, lptr)                                                  \
  __builtin_amdgcn_global_load_lds(                                              \
      (const __attribute__((address_space(1))) void*)(gptr),                     \
      (__attribute__((address_space(3))) void*)(lptr), 16, 0, 0)

__device__ __forceinline__ unsigned short f2bf(float f) {
  __hip_bfloat16 h = __float2bfloat16(f);
  return __builtin_bit_cast(unsigned short, h);
}

// max over the 32-lane group this lane belongs to (masks <32 never cross the
// 32-lane halves of a wave64)
__device__ __forceinline__ float groupmax32(float v) {
  v = fmaxf(v, __shfl_xor(v, 1));
  v = fmaxf(v, __shfl_xor(v, 2));
  v = fmaxf(v, __shfl_xor(v, 4));
  v = fmaxf(v, __shfl_xor(v, 8));
  v = fmaxf(v, __shfl_xor(v, 16));
  return v;
}

// Fake-quant 4 values (one lane's slice of a 128-elem block spread over 32
// lanes x 4 elems). Matches ref within margin: amax->clip 1e-12,
// scale=448/amax, clip(x*scale,+-448), RNE fp8 e4m3 (HW cvt, OCP on gfx950),
// deq = q * (amax/448)  [mul instead of divide; <=1ulp vs ref's q/scale].
__device__ __forceinline__ void fq_e4m3_4(const float* __restrict__ in,
                                          float* __restrict__ out) {
  float am = fmaxf(fmaxf(fabsf(in[0]), fabsf(in[1])),
                   fmaxf(fabsf(in[2]), fabsf(in[3])));
  am = groupmax32(am);
  am = fmaxf(am, 1e-12f);
  const float scale = 448.0f / am;            // one exact divide per 4 elems
  const float inv   = am * (1.0f / 448.0f);   // dequant multiplier
  float c0 = fminf(fmaxf(in[0] * scale, -448.0f), 448.0f);
  float c1 = fminf(fmaxf(in[1] * scale, -448.0f), 448.0f);
  float c2 = fminf(fmaxf(in[2] * scale, -448.0f), 448.0f);
  float c3 = fminf(fmaxf(in[3] * scale, -448.0f), 448.0f);
  int pk = __builtin_amdgcn_cvt_pk_fp8_f32(c0, c1, 0, false);
  pk = __builtin_amdgcn_cvt_pk_fp8_f32(c2, c3, pk, true);
  out[0] = __builtin_amdgcn_cvt_f32_fp8(pk, 0) * inv;
  out[1] = __builtin_amdgcn_cvt_f32_fp8(pk, 1) * inv;
  out[2] = __builtin_amdgcn_cvt_f32_fp8(pk, 2) * inv;
  out[3] = __builtin_amdgcn_cvt_f32_fp8(pk, 3) * inv;
}

// ---------- activation quant: 16 rows per block, unroll 4 for ILP ----------
#define XROWS 16
__global__ __launch_bounds__(256) void quant_x_k(const float* __restrict__ x,
                                                 unsigned short* __restrict__ xq) {
  const int tid = threadIdx.x;
  const size_t row0 = (size_t)blockIdx.x * XROWS;
#pragma unroll 4
  for (int j = 0; j < XROWS; ++j) {
    const size_t row = row0 + j;
    const float4 v = ((const float4*)(x + row * 1024))[tid];
    float in[4] = {v.x, v.y, v.z, v.w};
    float dq[4];
    fq_e4m3_4(in, dq);
    union { ushort4 u; unsigned short s[4]; } pk;
    pk.s[0] = f2bf(dq[0]); pk.s[1] = f2bf(dq[1]);
    pk.s[2] = f2bf(dq[2]); pk.s[3] = f2bf(dq[3]);
    ((ushort4*)(xq + row * 1024))[tid] = pk.u;
  }
}

// ---------- weight dual-quant: 4 rows per block ----------
#define WROWS 4
__global__ __launch_bounds__(256) void quant_w_k(const float* __restrict__ w,
                                                 unsigned short* __restrict__ wq) {
  const int tid = threadIdx.x;
  const size_t row0 = (size_t)blockIdx.x * WROWS;
#pragma unroll
  for (int j = 0; j < WROWS; ++j) {
    const size_t row = row0 + j;
    const float4 v = ((const float4*)(w + row * 1024))[tid];
    float in[4] = {v.x, v.y, v.z, v.w};
    float hi[4], res[4], lo[4];
    fq_e4m3_4(in, hi);
#pragma unroll
    for (int i = 0; i < 4; ++i) res[i] = in[i] - hi[i];
    fq_e4m3_4(res, lo);
    union { ushort4 u; unsigned short s[4]; } pk;
#pragma unroll
    for (int i = 0; i < 4; ++i) pk.s[i] = f2bf(hi[i] + lo[i]);
    ((ushort4*)(wq + row * 1024))[tid] = pk.u;
  }
}

// ---------- GEMM: C[M,N] = A[M,K] * B[N,K]^T + bias, bf16 in fp32 out ----
// LDS layout: row-major 128x64 bf16, 16B chunks XOR-swizzled within each row:
// slot s of row r holds global col-group (s ^ (r&7)). This makes the
// ds_read_b128 fragment reads hit all 8 four-bank groups (2 lanes each = free)
// instead of 16-way conflicting at the raw row*128B stride, while keeping the
// global_load_lds lane->base+lane*16B constraint satisfied.
#define BM 128
#define BN 128
#define BK 64

__global__ __launch_bounds__(256) void gemm_bt_bias(
    const unsigned short* __restrict__ A,   // bf16 bits [M,K]
    const unsigned short* __restrict__ B,   // bf16 bits [N,K]
    const float* __restrict__ bias,         // [N]
    float* __restrict__ C,                  // [M,N]
    int M, int N, int K) {
  __shared__ unsigned short ldsA[BM * BK];  // 16 KB
  __shared__ unsigned short ldsB[BN * BK];  // 16 KB

  const int tid  = threadIdx.x;
  const int wave = tid >> 6;
  const int lane = tid & 63;
  const int nbn  = N / BN;
  const int nbm  = M / BM;

  // XCD-aware swizzle: blocks round-robin to XCD (blk & 7). Give each XCD a
  // contiguous bm range, bn fastest -> the 8 blocks sharing an A-tile run
  // back-to-back on one XCD's L2 (A fetched once, not 8x).
  int bm, bn;
  if ((nbm & 7) == 0) {
    const int xcd = blockIdx.x & 7;
    const int j   = blockIdx.x >> 3;
    bn = j % nbn;
    bm = xcd * (nbm >> 3) + j / nbn;
  } else {
    bn = blockIdx.x % nbn;
    bm = blockIdx.x / nbn;
  }

  const int wr = wave >> 1;   // 0..1 (M dir)
  const int wc = wave & 1;    // 0..1 (N dir)

  f32x4 acc[4][4] = {};

  // staging: wave covers tile rows [wave*32, wave*32+32), 4 chunks of 8 rows.
  // lane i -> row (lane>>3); source col-group = (lane&7) ^ (lane>>3)  [swizzle]
  const int rload = wave * 32 + (lane >> 3);
  const int cload = (((lane & 7) ^ (lane >> 3)) * 8);
  const unsigned short* gA = A + (size_t)(bm * BM + rload) * K + cload;
  const unsigned short* gB = B + (size_t)(bn * BN + rload) * K + cload;
  unsigned short* lA = ldsA + wave * 2048 + lane * 8;
  unsigned short* lB = ldsB + wave * 2048 + lane * 8;

  for (int kt = 0; kt < K; kt += BK) {
    __syncthreads();
#pragma unroll
    for (int t = 0; t < 4; ++t) {
      GLOAD_LDS16(gA + (size_t)(t * 8) * K + kt, lA + t * 512);
      GLOAD_LDS16(gB + (size_t)(t * 8) * K + kt, lB + t * 512);
    }
    __syncthreads();

    const int fRow = lane & 15;
    const int sw   = fRow & 7;          // xor-swizzle key for this lane's rows
#pragma unroll
    for (int kc = 0; kc < 2; ++kc) {
      const int c = kc * 4 + (lane >> 4);       // col-group 0..7
      const int sOff = ((c ^ sw) * 8);          // swizzled chunk offset (elems)
      bf16x8 af[4], bfr[4];
#pragma unroll
      for (int i = 0; i < 4; ++i)
        af[i] = *(const bf16x8*)&ldsA[(wr * 64 + i * 16 + fRow) * BK + sOff];
#pragma unroll
      for (int j = 0; j < 4; ++j)
        bfr[j] = *(const bf16x8*)&ldsB[(wc * 64 + j * 16 + fRow) * BK + sOff];
#pragma unroll
      for (int i = 0; i < 4; ++i)
#pragma unroll
        for (int j = 0; j < 4; ++j)
          acc[i][j] = __builtin_amdgcn_mfma_f32_16x16x32_bf16(af[i], bfr[j],
                                                              acc[i][j], 0, 0, 0);
    }
  }

  // epilogue: C/D map col=lane&15, row=(lane>>4)*4+reg  [m89/m91 verified]
  const int    n0 = bn * BN + wc * 64 + (lane & 15);
  const size_t m0 = (size_t)bm * BM + wr * 64 + ((lane >> 4) << 2);
#pragma unroll
  for (int j = 0; j < 4; ++j) {
    const int col = n0 + j * 16;
    const float bv = bias[col];
#pragma unroll
    for (int i = 0; i < 4; ++i) {
      const size_t base = (m0 + (size_t)i * 16) * N + col;
#pragma unroll
      for (int r = 0; r < 4; ++r)
        C[base + (size_t)r * N] = acc[i][j][r] + bv;
    }
  }
}

// ---------- launch ----------
extern "C" void kernel_launch(void* const* d_in, const int* in_sizes, int n_in,
                              void* d_out, int out_size, void* d_ws, size_t ws_size,
                              hipStream_t stream) {
  const float* x    = (const float*)d_in[0];
  const float* w    = (const float*)d_in[1];
  const float* bias = (const float*)d_in[2];

  const int DOUT = in_sizes[2];            // 1024
  const int DIN  = in_sizes[1] / DOUT;     // 1024
  const int M    = in_sizes[0] / DIN;      // 32768

  unsigned short* xq = (unsigned short*)d_ws;                  // M*K bf16 = 64 MB
  unsigned short* wq = xq + (size_t)M * DIN;                   // N*K bf16 =  2 MB

  hipLaunchKernelGGL(quant_x_k, dim3(M / XROWS), dim3(256), 0, stream, x, xq);
  hipLaunchKernelGGL(quant_w_k, dim3(DOUT / WROWS), dim3(256), 0, stream, w, wq);

  const int grid = (M / BM) * (DOUT / BN);
  hipLaunchKernelGGL(gemm_bt_bias, dim3(grid), dim3(256), 0, stream,
                     xq, wq, bias, (float*)d_out, M, DOUT, DIN);
}

// Round 3
// 320.346 us; speedup vs baseline: 1.0293x; 1.0258x over previous
//
#include <hip/hip_runtime.h>
#include <hip/hip_bf16.h>

// ---------- types ----------
typedef __bf16 bf16x8 __attribute__((ext_vector_type(8)));
typedef float  f32x4  __attribute__((ext_vector_type(4)));

#define GLOAD_LDS16(gptr, lptr)                                                  \
  __builtin_amdgcn_global_load_lds(                                              \
      (const __attribute__((address_space(1))) void*)(gptr),                     \
      (__attribute__((address_space(3))) void*)(lptr), 16, 0, 0)

__device__ __forceinline__ unsigned short f2bf(float f) {
  __hip_bfloat16 h = __float2bfloat16(f);
  return __builtin_bit_cast(unsigned short, h);
}

// ---------- fake-quant of one 128-elem block held by a 4-lane quad ----------
// Each lane owns 32 consecutive floats. Ref math: amax=clip(max|x|,1e-12),
// scale=448/amax, q=RNE_fp8(clip(x*scale,+-448)) [HW cvt, OCP e4m3],
// deq=q*(amax/448) [mul vs ref's divide: <=1ulp, margin is 4.5x].
__device__ __forceinline__ void fq32(float* __restrict__ v) {
  float am = 0.0f;
#pragma unroll
  for (int i = 0; i < 32; ++i) am = fmaxf(am, fabsf(v[i]));
  am = fmaxf(am, __shfl_xor(am, 1));   // quad reduction: DPP, no LDS
  am = fmaxf(am, __shfl_xor(am, 2));
  am = fmaxf(am, 1e-12f);
  const float scale = 448.0f / am;
  const float inv   = am * (1.0f / 448.0f);
#pragma unroll
  for (int i = 0; i < 32; i += 4) {
    float c0 = fminf(fmaxf(v[i + 0] * scale, -448.0f), 448.0f);
    float c1 = fminf(fmaxf(v[i + 1] * scale, -448.0f), 448.0f);
    float c2 = fminf(fmaxf(v[i + 2] * scale, -448.0f), 448.0f);
    float c3 = fminf(fmaxf(v[i + 3] * scale, -448.0f), 448.0f);
    int pk = __builtin_amdgcn_cvt_pk_fp8_f32(c0, c1, 0, false);
    pk = __builtin_amdgcn_cvt_pk_fp8_f32(c2, c3, pk, true);
    v[i + 0] = __builtin_amdgcn_cvt_f32_fp8(pk, 0) * inv;
    v[i + 1] = __builtin_amdgcn_cvt_f32_fp8(pk, 1) * inv;
    v[i + 2] = __builtin_amdgcn_cvt_f32_fp8(pk, 2) * inv;
    v[i + 3] = __builtin_amdgcn_cvt_f32_fp8(pk, 3) * inv;
  }
}

// ---------- activation quant (K=1024: 8 blocks/row x 4 lanes = 32 thr/row) --
__global__ __launch_bounds__(256) void quant_x_k(const float* __restrict__ x,
                                                 unsigned short* __restrict__ xq) {
  const size_t u   = (size_t)blockIdx.x * 256 + threadIdx.x;
  const size_t off = u * 32;               // row*1024 + kb*128 + part*32
  float v[32];
#pragma unroll
  for (int i = 0; i < 8; ++i)
    *(float4*)&v[i * 4] = ((const float4*)(x + off))[i];
  fq32(v);
  union { uint4 q; unsigned short s[8]; } pk;
#pragma unroll
  for (int g = 0; g < 4; ++g) {
#pragma unroll
    for (int e = 0; e < 8; ++e) pk.s[e] = f2bf(v[g * 8 + e]);
    ((uint4*)(xq + off))[g] = pk.q;
  }
}

// ---------- weight dual-quant: hi + fp8(residual) ----------
__global__ __launch_bounds__(256) void quant_w_k(const float* __restrict__ w,
                                                 unsigned short* __restrict__ wq) {
  const size_t u   = (size_t)blockIdx.x * 256 + threadIdx.x;
  const size_t off = u * 32;
  float a[32], h[32], r[32];
#pragma unroll
  for (int i = 0; i < 8; ++i)
    *(float4*)&a[i * 4] = ((const float4*)(w + off))[i];
#pragma unroll
  for (int i = 0; i < 32; ++i) h[i] = a[i];
  fq32(h);
#pragma unroll
  for (int i = 0; i < 32; ++i) r[i] = a[i] - h[i];
  fq32(r);
  union { uint4 q; unsigned short s[8]; } pk;
#pragma unroll
  for (int g = 0; g < 4; ++g) {
#pragma unroll
    for (int e = 0; e < 8; ++e) pk.s[e] = f2bf(h[g * 8 + e] + r[g * 8 + e]);
    ((uint4*)(wq + off))[g] = pk.q;
  }
}

// ---------- GEMM: C[M,N] = A[M,K] * B[N,K]^T + bias, bf16 in fp32 out ----
// Double-buffered LDS (2x32KB), ONE barrier per K-iter: the vmcnt(0) drain at
// each barrier waits on loads that had a full compute phase in flight.
// 16B chunks XOR-swizzled within each row (slot s holds col-group s^(r&7)):
// measured 0 bank conflicts. XCD swizzle: 8 bn-blocks sharing an A-tile run
// consecutively on one XCD's L2 (FETCH at ideal 66 MB).
#define BM 128
#define BN 128
#define BK 64

__global__ __launch_bounds__(256) void gemm_bt_bias(
    const unsigned short* __restrict__ A,   // bf16 bits [M,K]
    const unsigned short* __restrict__ B,   // bf16 bits [N,K]
    const float* __restrict__ bias,         // [N]
    float* __restrict__ C,                  // [M,N]
    int M, int N, int K) {
  __shared__ unsigned short ldsA[2 * BM * BK];  // 32 KB
  __shared__ unsigned short ldsB[2 * BN * BK];  // 32 KB

  const int tid  = threadIdx.x;
  const int wave = tid >> 6;
  const int lane = tid & 63;
  const int nbn  = N / BN;
  const int nbm  = M / BM;

  int bm, bn;
  if ((nbm & 7) == 0) {
    const int xcd = blockIdx.x & 7;
    const int j   = blockIdx.x >> 3;
    bn = j % nbn;
    bm = xcd * (nbm >> 3) + j / nbn;
  } else {
    bn = blockIdx.x % nbn;
    bm = blockIdx.x / nbn;
  }

  const int wr = wave >> 1;   // 0..1 (M dir)
  const int wc = wave & 1;    // 0..1 (N dir)

  f32x4 acc[4][4] = {};

  // staging: wave covers tile rows [wave*32, wave*32+32), 4 chunks of 8 rows.
  // lane i -> row (lane>>3); source col-group = (lane&7)^(lane>>3)  [swizzle]
  const int rload = wave * 32 + (lane >> 3);
  const int cload = (((lane & 7) ^ (lane >> 3)) * 8);
  const unsigned short* gA = A + (size_t)(bm * BM + rload) * K + cload;
  const unsigned short* gB = B + (size_t)(bn * BN + rload) * K + cload;
  unsigned short* lA = ldsA + wave * 2048 + lane * 8;
  unsigned short* lB = ldsB + wave * 2048 + lane * 8;

  auto stage = [&](int it, int buf) {
    const unsigned short* pA = gA + (size_t)it * BK;
    const unsigned short* pB = gB + (size_t)it * BK;
    unsigned short* dA = lA + buf * (BM * BK);
    unsigned short* dB = lB + buf * (BN * BK);
#pragma unroll
    for (int t = 0; t < 4; ++t) {
      GLOAD_LDS16(pA + (size_t)(t * 8) * K, dA + t * 512);
      GLOAD_LDS16(pB + (size_t)(t * 8) * K, dB + t * 512);
    }
  };

  auto compute = [&](const unsigned short* bA, const unsigned short* bB) {
    const int fRow = lane & 15;
    const int sw   = fRow & 7;
#pragma unroll
    for (int kc = 0; kc < 2; ++kc) {
      const int c    = kc * 4 + (lane >> 4);   // col-group 0..7
      const int sOff = ((c ^ sw) * 8);
      bf16x8 af[4], bfr[4];
#pragma unroll
      for (int i = 0; i < 4; ++i)
        af[i] = *(const bf16x8*)&bA[(wr * 64 + i * 16 + fRow) * BK + sOff];
#pragma unroll
      for (int j = 0; j < 4; ++j)
        bfr[j] = *(const bf16x8*)&bB[(wc * 64 + j * 16 + fRow) * BK + sOff];
#pragma unroll
      for (int i = 0; i < 4; ++i)
#pragma unroll
        for (int j = 0; j < 4; ++j)
          acc[i][j] = __builtin_amdgcn_mfma_f32_16x16x32_bf16(af[i], bfr[j],
                                                              acc[i][j], 0, 0, 0);
    }
  };

  stage(0, 0);
  const int niter = K / BK;   // 16 (even; required by the 2x unroll below)
  for (int it = 0; it < niter; it += 2) {
    __syncthreads();                       // drains buf0 loads; readers of buf1 done
    if (it + 1 < niter) stage(it + 1, 1);  // prefetch next tile into buf1
    compute(ldsA, ldsB);
    __syncthreads();                       // drains buf1 loads; readers of buf0 done
    if (it + 2 < niter) stage(it + 2, 0);  // prefetch into buf0
    compute(ldsA + BM * BK, ldsB + BN * BK);
  }

  // epilogue: C/D map col=lane&15, row=(lane>>4)*4+reg  [m89/m91 verified]
  const int    n0 = bn * BN + wc * 64 + (lane & 15);
  const size_t m0 = (size_t)bm * BM + wr * 64 + ((lane >> 4) << 2);
#pragma unroll
  for (int j = 0; j < 4; ++j) {
    const int col = n0 + j * 16;
    const float bv = bias[col];
#pragma unroll
    for (int i = 0; i < 4; ++i) {
      const size_t base = (m0 + (size_t)i * 16) * N + col;
#pragma unroll
      for (int r = 0; r < 4; ++r)
        C[base + (size_t)r * N] = acc[i][j][r] + bv;
    }
  }
}

// ---------- launch ----------
extern "C" void kernel_launch(void* const* d_in, const int* in_sizes, int n_in,
                              void* d_out, int out_size, void* d_ws, size_t ws_size,
                              hipStream_t stream) {
  const float* x    = (const float*)d_in[0];
  const float* w    = (const float*)d_in[1];
  const float* bias = (const float*)d_in[2];

  const int DOUT = in_sizes[2];            // 1024
  const int DIN  = in_sizes[1] / DOUT;     // 1024
  const int M    = in_sizes[0] / DIN;      // 32768

  unsigned short* xq = (unsigned short*)d_ws;                  // M*K bf16 = 64 MB
  unsigned short* wq = xq + (size_t)M * DIN;                   // N*K bf16 =  2 MB

  // 32 floats per thread -> M*DIN/32 threads
  hipLaunchKernelGGL(quant_x_k, dim3((size_t)M * DIN / 32 / 256), dim3(256), 0,
                     stream, x, xq);
  hipLaunchKernelGGL(quant_w_k, dim3((size_t)DOUT * DIN / 32 / 256), dim3(256), 0,
                     stream, w, wq);

  const int grid = (M / BM) * (DOUT / BN);
  hipLaunchKernelGGL(gemm_bt_bias, dim3(grid), dim3(256), 0, stream,
                     xq, wq, bias, (float*)d_out, M, DOUT, DIN);
}